// Round 2
// baseline (890.503 us; speedup 1.0000x reference)
//
#include <hip/hip_runtime.h>
#include <hip/hip_bf16.h>

// Problem: B=2, S=2048, HID=1024, NH=16, HD=64. fp32 in/out (per reference).
// d_out = [out (2*2048*1024) | attn (2*16*2048*2048)] fp32.
#define BB   2
#define SS   2048
#define HID  1024
#define NH   16
#define HD   64
#define NEGS -30000.0f

typedef __bf16 bf16x8 __attribute__((ext_vector_type(8)));
typedef float  f32x4  __attribute__((ext_vector_type(4)));

static __device__ __forceinline__ f32x4 mfma_bf16(bf16x8 a, bf16x8 b, f32x4 c) {
    return __builtin_amdgcn_mfma_f32_16x16x32_bf16(a, b, c, 0, 0, 0);
}

static __device__ __forceinline__ void split_bf16(float f, __bf16* hp, __bf16* lp) {
    __bf16 h = (__bf16)f;
    *hp = h;
    *lp = (__bf16)(f - (float)h);
}

static __device__ __forceinline__ float clampf(float v, float lo, float hi) {
    return fminf(fmaxf(v, lo), hi);   // also scrubs NaN -> lo
}

// ---------------------------------------------------------------------------
// K1: QKV projection from fp32 x, W.  out[t][o] = sum_c x[t][c]*W[o][c] + b[o]
// Q,K: hi/lo split of BOTH operands in LDS, 3-chain MFMA (fp32-grade).
// V:   hi-only MFMA (bf16-grade is fine downstream).
// qh/ql = hi/lo bf16 split of 8*(x@Wq^T+bq), layout [bh][s][d]
// kh/kl = hi/lo split of (x@Wk^T+bk),        layout [bh][s][d]
// vt    = bf16 (x@Wv^T+bv) transposed,       layout [bh][d][s]
// ---------------------------------------------------------------------------
__global__ __launch_bounds__(256) void qkv_kernel(
    const float* __restrict__ x,
    const float* __restrict__ Wq, const float* __restrict__ bq,
    const float* __restrict__ Wk, const float* __restrict__ bk,
    const float* __restrict__ Wv, const float* __restrict__ bv,
    __bf16* __restrict__ qh, __bf16* __restrict__ ql,
    __bf16* __restrict__ kh, __bf16* __restrict__ kl,
    __bf16* __restrict__ vt)
{
    __shared__ __align__(16) __bf16 Ash[64][40], Asl[64][40];
    __shared__ __align__(16) __bf16 Bsh[64][40], Bsl[64][40];
    __shared__ __align__(16) __bf16 Vts[64][72];

    const int nt = blockIdx.x;            // 0..47
    const int mt = blockIdx.y;            // 0..63
    const int stream_id = nt >> 4;        // 0=q 1=k 2=v
    const int h  = nt & 15;
    const int o0 = h * 64;
    const float* W  = stream_id == 0 ? Wq : (stream_id == 1 ? Wk : Wv);
    const float* bi = stream_id == 0 ? bq : (stream_id == 1 ? bk : bv);

    const int tid  = threadIdx.x;
    const int wave = tid >> 6, lane = tid & 63;
    const int l16  = lane & 15, quad = lane >> 4;

    const f32x4 zero4 = {0.f, 0.f, 0.f, 0.f};
    f32x4 acc[4] = {zero4, zero4, zero4, zero4};

    const int arow = tid >> 2, ac4 = tid & 3;          // 8 fp32 elems / thread
    const size_t xoff = (size_t)(mt * 64 + arow) * HID + ac4 * 8;
    const size_t woff = (size_t)(o0 + arow) * HID + ac4 * 8;

    for (int k0 = 0; k0 < HID; k0 += 32) {
        __syncthreads();
        float4 a0 = *(const float4*)&x[xoff + k0];
        float4 a1 = *(const float4*)&x[xoff + k0 + 4];
        float4 b0 = *(const float4*)&W[woff + k0];
        float4 b1 = *(const float4*)&W[woff + k0 + 4];
        const float* pa0 = (const float*)&a0;
        const float* pa1 = (const float*)&a1;
        const float* pb0 = (const float*)&b0;
        const float* pb1 = (const float*)&b1;
#pragma unroll
        for (int j = 0; j < 4; j++) {
            split_bf16(pa0[j], &Ash[arow][ac4*8 + j],     &Asl[arow][ac4*8 + j]);
            split_bf16(pa1[j], &Ash[arow][ac4*8 + 4 + j], &Asl[arow][ac4*8 + 4 + j]);
            split_bf16(pb0[j], &Bsh[arow][ac4*8 + j],     &Bsl[arow][ac4*8 + j]);
            split_bf16(pb1[j], &Bsh[arow][ac4*8 + 4 + j], &Bsl[arow][ac4*8 + 4 + j]);
        }
        __syncthreads();
        bf16x8 aH = *(const bf16x8*)&Ash[wave * 16 + l16][quad * 8];
        bf16x8 aL = *(const bf16x8*)&Asl[wave * 16 + l16][quad * 8];
#pragma unroll
        for (int c = 0; c < 4; c++) {
            bf16x8 bH = *(const bf16x8*)&Bsh[c * 16 + l16][quad * 8];
            acc[c] = mfma_bf16(aH, bH, acc[c]);
            if (stream_id < 2) {
                bf16x8 bL = *(const bf16x8*)&Bsl[c * 16 + l16][quad * 8];
                acc[c] = mfma_bf16(aH, bL, acc[c]);
                acc[c] = mfma_bf16(aL, bH, acc[c]);
            }
        }
    }

    const int t0 = mt * 64;
    const int bidx = t0 >> 11;            // batch
    const int s0 = t0 & (SS - 1);

    if (stream_id < 2) {
        __bf16* hi_arr = stream_id == 0 ? qh : kh;
        __bf16* lo_arr = stream_id == 0 ? ql : kl;
        const float scale = stream_id == 0 ? 8.0f : 1.0f;   // score scale on q
#pragma unroll
        for (int c = 0; c < 4; c++) {
            const int d = c * 16 + l16;
            const float bias = bi[o0 + d];
#pragma unroll
            for (int r = 0; r < 4; r++) {
                const int srow = s0 + wave * 16 + quad * 4 + r;
                float v = clampf((acc[c][r] + bias) * scale, -1e4f, 1e4f);
                __bf16 hv, lv;
                split_bf16(v, &hv, &lv);
                const size_t o = ((size_t)(bidx * NH + h) * SS + srow) * HD + d;
                hi_arr[o] = hv;
                lo_arr[o] = lv;
            }
        }
    } else {
        // V: transpose 64x64 tile through LDS, store vt[bh][d][s]
#pragma unroll
        for (int c = 0; c < 4; c++) {
            const int d = c * 16 + l16;
            const float bias = bi[o0 + d];
#pragma unroll
            for (int r = 0; r < 4; r++)
                Vts[d][wave * 16 + quad * 4 + r] =
                    (__bf16)clampf(acc[c][r] + bias, -1e4f, 1e4f);
        }
        __syncthreads();
#pragma unroll
        for (int i = 0; i < 2; i++) {
            const int idx = tid + i * 256;
            const int d = idx >> 3, c8 = idx & 7;
            const size_t o = ((size_t)(bidx * NH + h) * HD + d) * SS + s0 + c8 * 8;
            *(uint4*)&vt[o] = *(const uint4*)&Vts[d][c8 * 8];
        }
    }
}

// ---------------------------------------------------------------------------
// K2: causal attention, block = (bh, 64-row q-tile), two-pass online softmax.
// attn written fp32; ctx written bf16 to ws.
// ---------------------------------------------------------------------------
__global__ __launch_bounds__(256) void attn_kernel(
    const __bf16* __restrict__ qh, const __bf16* __restrict__ ql,
    const __bf16* __restrict__ kh, const __bf16* __restrict__ kl,
    const __bf16* __restrict__ vt,
    float* __restrict__ attn, __bf16* __restrict__ ctx)
{
    __shared__ __align__(16) __bf16 Qh[64][72], Ql[64][72];
    __shared__ __align__(16) __bf16 Kh[64][72], Kl[64][72];
    __shared__ __align__(16) __bf16 Vt[64][72], Ps[64][72];

    const int bid = blockIdx.x;
    const int bh = bid >> 5;              // b*NH + h
    const int qt = bid & 31;
    const int b = bh >> 4, h = bh & 15;

    const int tid  = threadIdx.x;
    const int wave = tid >> 6, lane = tid & 63;
    const int l16  = lane & 15, quad = lane >> 4;

    {
        const size_t base = ((size_t)bh * SS + qt * 64) * HD;
#pragma unroll
        for (int i = 0; i < 2; i++) {
            const int idx = tid + i * 256;
            const int row = idx >> 3, c8 = idx & 7;
            *(uint4*)&Qh[row][c8 * 8] = *(const uint4*)&qh[base + row * HD + c8 * 8];
            *(uint4*)&Ql[row][c8 * 8] = *(const uint4*)&ql[base + row * HD + c8 * 8];
        }
    }

    float m4[4], l4[4];
#pragma unroll
    for (int r = 0; r < 4; r++) { m4[r] = NEGS; l4[r] = 0.f; }

    const f32x4 zero4 = {0.f, 0.f, 0.f, 0.f};

    // ---- pass A: row max & sumexp ----
    for (int kt = 0; kt <= qt; kt++) {
        __syncthreads();
        const size_t base = ((size_t)bh * SS + kt * 64) * HD;
#pragma unroll
        for (int i = 0; i < 2; i++) {
            const int idx = tid + i * 256;
            const int row = idx >> 3, c8 = idx & 7;
            *(uint4*)&Kh[row][c8 * 8] = *(const uint4*)&kh[base + row * HD + c8 * 8];
            *(uint4*)&Kl[row][c8 * 8] = *(const uint4*)&kl[base + row * HD + c8 * 8];
        }
        __syncthreads();

        f32x4 sacc[4] = {zero4, zero4, zero4, zero4};
#pragma unroll
        for (int ks = 0; ks < 2; ks++) {
            bf16x8 aH = *(const bf16x8*)&Qh[wave * 16 + l16][ks * 32 + quad * 8];
            bf16x8 aL = *(const bf16x8*)&Ql[wave * 16 + l16][ks * 32 + quad * 8];
#pragma unroll
            for (int c = 0; c < 4; c++) {
                bf16x8 bH = *(const bf16x8*)&Kh[c * 16 + l16][ks * 32 + quad * 8];
                bf16x8 bL = *(const bf16x8*)&Kl[c * 16 + l16][ks * 32 + quad * 8];
                sacc[c] = mfma_bf16(aH, bH, sacc[c]);
                sacc[c] = mfma_bf16(aH, bL, sacc[c]);
                sacc[c] = mfma_bf16(aL, bH, sacc[c]);
            }
        }
        if (kt == qt) {
#pragma unroll
            for (int c = 0; c < 4; c++) {
                const int col = c * 16 + l16;
#pragma unroll
                for (int r = 0; r < 4; r++)
                    if (col > wave * 16 + quad * 4 + r) sacc[c][r] = NEGS;
            }
        }
#pragma unroll
        for (int r = 0; r < 4; r++) {
            float mx = fmaxf(fmaxf(sacc[0][r], sacc[1][r]), fmaxf(sacc[2][r], sacc[3][r]));
#pragma unroll
            for (int off = 1; off < 16; off <<= 1) mx = fmaxf(mx, __shfl_xor(mx, off));
            const float mn = fmaxf(m4[r], mx);
            float se = __expf(sacc[0][r] - mn) + __expf(sacc[1][r] - mn)
                     + __expf(sacc[2][r] - mn) + __expf(sacc[3][r] - mn);
#pragma unroll
            for (int off = 1; off < 16; off <<= 1) se += __shfl_xor(se, off);
            l4[r] = l4[r] * __expf(m4[r] - mn) + se;
            m4[r] = mn;
        }
    }

    float il[4];
#pragma unroll
    for (int r = 0; r < 4; r++) il[r] = (l4[r] > 0.f) ? (1.0f / l4[r]) : 0.f;

    f32x4 cacc[4] = {zero4, zero4, zero4, zero4};

    // ---- pass B: attn write (fp32) + ctx accumulate ----
    for (int kt = 0; kt <= qt; kt++) {
        __syncthreads();
        const size_t kbase = ((size_t)bh * SS + kt * 64) * HD;
        const size_t vbase = (size_t)bh * HD * SS + kt * 64;
#pragma unroll
        for (int i = 0; i < 2; i++) {
            const int idx = tid + i * 256;
            const int row = idx >> 3, c8 = idx & 7;
            *(uint4*)&Kh[row][c8 * 8] = *(const uint4*)&kh[kbase + row * HD + c8 * 8];
            *(uint4*)&Kl[row][c8 * 8] = *(const uint4*)&kl[kbase + row * HD + c8 * 8];
            *(uint4*)&Vt[row][c8 * 8] = *(const uint4*)&vt[vbase + (size_t)row * SS + c8 * 8];
        }
        __syncthreads();

        f32x4 sacc[4] = {zero4, zero4, zero4, zero4};
#pragma unroll
        for (int ks = 0; ks < 2; ks++) {
            bf16x8 aH = *(const bf16x8*)&Qh[wave * 16 + l16][ks * 32 + quad * 8];
            bf16x8 aL = *(const bf16x8*)&Ql[wave * 16 + l16][ks * 32 + quad * 8];
#pragma unroll
            for (int c = 0; c < 4; c++) {
                bf16x8 bH = *(const bf16x8*)&Kh[c * 16 + l16][ks * 32 + quad * 8];
                bf16x8 bL = *(const bf16x8*)&Kl[c * 16 + l16][ks * 32 + quad * 8];
                sacc[c] = mfma_bf16(aH, bH, sacc[c]);
                sacc[c] = mfma_bf16(aH, bL, sacc[c]);
                sacc[c] = mfma_bf16(aL, bH, sacc[c]);
            }
        }
        if (kt == qt) {
#pragma unroll
            for (int c = 0; c < 4; c++) {
                const int col = c * 16 + l16;
#pragma unroll
                for (int r = 0; r < 4; r++)
                    if (col > wave * 16 + quad * 4 + r) sacc[c][r] = NEGS;
            }
        }
#pragma unroll
        for (int c = 0; c < 4; c++) {
#pragma unroll
            for (int r = 0; r < 4; r++) {
                float p = clampf(__expf(sacc[c][r] - m4[r]) * il[r], 0.f, 1.f);
                Ps[wave * 16 + quad * 4 + r][c * 16 + l16] = (__bf16)p;
            }
        }
        __syncthreads();
        // coalesced fp32 attn store (upconvert the same bf16 P used for P·V)
#pragma unroll
        for (int i = 0; i < 2; i++) {
            const int idx = tid + i * 256;
            const int row = idx >> 3, c8 = idx & 7;
            const size_t o = ((size_t)bh * SS + qt * 64 + row) * SS + kt * 64 + c8 * 8;
            __bf16 tmp[8];
            *(uint4*)tmp = *(const uint4*)&Ps[row][c8 * 8];
            float4 f0, f1;
            f0.x = (float)tmp[0]; f0.y = (float)tmp[1];
            f0.z = (float)tmp[2]; f0.w = (float)tmp[3];
            f1.x = (float)tmp[4]; f1.y = (float)tmp[5];
            f1.z = (float)tmp[6]; f1.w = (float)tmp[7];
            *(float4*)&attn[o]     = f0;
            *(float4*)&attn[o + 4] = f1;
        }
        // ctx += P @ V
#pragma unroll
        for (int ks = 0; ks < 2; ks++) {
            bf16x8 ap = *(const bf16x8*)&Ps[wave * 16 + l16][ks * 32 + quad * 8];
#pragma unroll
            for (int dt = 0; dt < 4; dt++) {
                bf16x8 bv8 = *(const bf16x8*)&Vt[dt * 16 + l16][ks * 32 + quad * 8];
                cacc[dt] = mfma_bf16(ap, bv8, cacc[dt]);
            }
        }
    }

    // zero-fill upper-triangle tiles (fp32)
    const float4 zf4 = {0.f, 0.f, 0.f, 0.f};
    for (int kt = qt + 1; kt < SS / 64; kt++) {
#pragma unroll
        for (int i = 0; i < 4; i++) {
            const int idx = tid + i * 256;          // [0,1024)
            const int row = idx >> 4, c4 = idx & 15;
            const size_t o = ((size_t)bh * SS + qt * 64 + row) * SS + kt * 64 + c4 * 4;
            *(float4*)&attn[o] = zf4;
        }
    }

    // ctx epilogue: [b][s][h*64+d] bf16
#pragma unroll
    for (int dt = 0; dt < 4; dt++) {
        const int d = dt * 16 + l16;
#pragma unroll
        for (int r = 0; r < 4; r++) {
            const int srow = qt * 64 + wave * 16 + quad * 4 + r;
            ctx[(size_t)(b * SS + srow) * HID + h * 64 + d] =
                (__bf16)clampf(cacc[dt][r], -1e4f, 1e4f);
        }
    }
}

// ---------------------------------------------------------------------------
// K3: out = ctx @ Wo^T + bo   (ctx bf16 in ws, Wo fp32 -> bf16-hi in LDS)
// ---------------------------------------------------------------------------
__global__ __launch_bounds__(256) void out_kernel(
    const __bf16* __restrict__ ctx, const float* __restrict__ Wo,
    const float* __restrict__ bo, float* __restrict__ out)
{
    __shared__ __align__(16) __bf16 As[64][40];
    __shared__ __align__(16) __bf16 Bs[64][40];

    const int nt = blockIdx.x;   // 0..15
    const int mt = blockIdx.y;   // 0..63
    const int o0 = nt * 64;

    const int tid  = threadIdx.x;
    const int wave = tid >> 6, lane = tid & 63;
    const int l16  = lane & 15, quad = lane >> 4;

    const f32x4 zero4 = {0.f, 0.f, 0.f, 0.f};
    f32x4 acc[4] = {zero4, zero4, zero4, zero4};

    const int arow = tid >> 2, ac4 = tid & 3;
    const size_t aoff = (size_t)(mt * 64 + arow) * HID + ac4 * 8;
    const size_t woff = (size_t)(o0 + arow) * HID + ac4 * 8;

    for (int k0 = 0; k0 < HID; k0 += 32) {
        __syncthreads();
        *(uint4*)&As[arow][ac4 * 8] = *(const uint4*)&ctx[aoff + k0];
        float4 b0 = *(const float4*)&Wo[woff + k0];
        float4 b1 = *(const float4*)&Wo[woff + k0 + 4];
        const float* pb0 = (const float*)&b0;
        const float* pb1 = (const float*)&b1;
#pragma unroll
        for (int j = 0; j < 4; j++) {
            Bs[arow][ac4 * 8 + j]     = (__bf16)pb0[j];
            Bs[arow][ac4 * 8 + 4 + j] = (__bf16)pb1[j];
        }
        __syncthreads();
        bf16x8 a = *(const bf16x8*)&As[wave * 16 + l16][quad * 8];
#pragma unroll
        for (int c = 0; c < 4; c++) {
            bf16x8 b = *(const bf16x8*)&Bs[c * 16 + l16][quad * 8];
            acc[c] = mfma_bf16(a, b, acc[c]);
        }
    }

#pragma unroll
    for (int c = 0; c < 4; c++) {
        const int d = o0 + c * 16 + l16;
        const float bias = bo[d];
#pragma unroll
        for (int r = 0; r < 4; r++) {
            const int t = mt * 64 + wave * 16 + quad * 4 + r;
            out[(size_t)t * HID + d] = clampf(acc[c][r] + bias, -1e4f, 1e4f);
        }
    }
}

extern "C" void kernel_launch(void* const* d_in, const int* in_sizes, int n_in,
                              void* d_out, int out_size, void* d_ws, size_t ws_size,
                              hipStream_t stream) {
    const float* x  = (const float*)d_in[0];
    const float* Wq = (const float*)d_in[1];
    const float* bq = (const float*)d_in[2];
    const float* Wk = (const float*)d_in[3];
    const float* bk = (const float*)d_in[4];
    const float* Wv = (const float*)d_in[5];
    const float* bv = (const float*)d_in[6];
    const float* Wo = (const float*)d_in[7];
    const float* bo = (const float*)d_in[8];

    float* out  = (float*)d_out;
    float* attn = out + (size_t)BB * SS * HID;

    const size_t NQ = (size_t)BB * NH * SS * HD;  // 4,194,304 elems per tensor
    __bf16* ws  = (__bf16*)d_ws;
    __bf16* qh  = ws;
    __bf16* ql  = qh + NQ;
    __bf16* kh  = ql + NQ;
    __bf16* kl  = kh + NQ;
    __bf16* vt  = kl + NQ;
    __bf16* ctx = vt + NQ;                        // total 6*NQ*2B = 50.3 MB

    qkv_kernel<<<dim3(48, 64), 256, 0, stream>>>(x, Wq, bq, Wk, bk, Wv, bv,
                                                 qh, ql, kh, kl, vt);
    attn_kernel<<<dim3(1024), 256, 0, stream>>>(qh, ql, kh, kl, vt, attn, ctx);
    out_kernel<<<dim3(16, 64), 256, 0, stream>>>(ctx, Wo, bo, out);
}